// Round 3
// baseline (1064.048 us; speedup 1.0000x reference)
//
#include <hip/hip_runtime.h>

// out[b,c,y,x] = sum_{dy,dx in [0,13)} aff[b, dy*13+dx, y, x] * in2_zp[b, c, y+dy-6, x+dx-6]
// B=4 C=64 H=W=192 D=169.
//
// Round 3: conflict-free-by-construction lane mapping.
//   lane l -> cg = l&7 (channel group), xs = l>>3 (x slot); thread owns
//   channels c = cg + 8i (i=0..7, strided) and 4 x's (x0 = X0 + 32*wave + 4*xs).
//   LDS row pitch 132 (132%32==4, 8*132%32==0): window b128 read bank-quad
//   = (cg + xs + k) % 8 -> exactly 8 lanes/quad = 8-phase minimum, 0 conflicts.
// Block = all 64 channels x 96-wide x-half -> aff fetched once (round 2 fetched
// it twice). __launch_bounds__(192,3): VGPR cap 170 for acc32+A52+w20 (~140),
// 12 waves/CU (round 2 measured ~5).

#define KD   6
#define WIN  13
#define ND   169
#define NB   4
#define NC   64
#define NH   192
#define NW   192
#define XH   96     // x-half width per block
#define PITCH 132   // LDS row pitch in floats: >=112, ==4 (mod 32)
#define NTH  192    // 3 waves

__global__ __launch_bounds__(NTH, 3)
void mxassemble(const float* __restrict__ aff,
                const float* __restrict__ in2,
                float* __restrict__ out) {
    __shared__ float lds[NC * PITCH];   // 33792 B -> 4 blocks/CU

    const int y    = blockIdx.x;
    const int half = blockIdx.y;
    const int b    = blockIdx.z;
    const int t    = threadIdx.x;
    const int l    = t & 63;
    const int wv   = t >> 6;            // wave 0..2
    const int cg   = l & 7;             // channel group 0..7
    const int xs   = l >> 3;            // x slot 0..7
    const int X0   = half * XH;
    const int x0   = X0 + wv * 32 + xs * 4;

    // LDS j-index 0 corresponds to global x = X0 - 8; j in [0,112).
    // Pre-zero the single 8-float OOB apron per row (left for half 0,
    // right for half 1); staging never touches it again.
    {
        const int jz0 = (half == 0) ? 0 : 104;
        for (int i = t; i < NC * 2; i += NTH) {
            const int c = i >> 1;
            const int q = i & 1;
            *(float4*)&lds[c * PITCH + jz0 + 4 * q] =
                make_float4(0.f, 0.f, 0.f, 0.f);
        }
    }

    float acc[8][4];
#pragma unroll
    for (int i = 0; i < 8; ++i)
#pragma unroll
        for (int j = 0; j < 4; ++j) acc[i][j] = 0.f;

    const float* in2_b = in2 + (size_t)b * NC * NH * NW;
    const float* aff_p = aff + (size_t)b * ND * NH * NW + (size_t)y * NW;

    for (int dy = 0; dy < WIN; ++dy) {
        const int r = y + dy - KD;
        const bool valid = (r >= 0) && (r < NH);   // block-uniform

        __syncthreads();   // previous iteration's readers done
        if (valid) {
            // Stage in2[b, :, r, X0-8 .. X0+104) -> LDS rows (b128 writes).
            // Bank-quad of write = (c%8 + q) % 8 -> near-even spread.
            for (int i = t; i < NC * 28; i += NTH) {
                const int c  = i / 28;
                const int q  = i - c * 28;
                const int xg = X0 - 8 + 4 * q;       // global x of this float4
                if (xg >= 0 && xg < NW) {
                    const float4 v =
                        *(const float4*)&in2_b[((size_t)c * NH + r) * NW + xg];
                    *(float4*)&lds[c * PITCH + 4 * q] = v;
                }
            }
        }
        __syncthreads();
        if (!valid) continue;   // zero-padded row contributes nothing

        // aff[b, dy*13+dx, y, x0..x0+3] -> A[13][4] (52 VGPRs, reused 8x;
        // 8 cg lanes share each value -> L1-merged loads).
        float A[WIN][4];
        {
            const float* ap = aff_p + (size_t)(dy * WIN) * NH * NW + x0;
#pragma unroll
            for (int dx = 0; dx < WIN; ++dx) {
                const float4 v = *(const float4*)&ap[(size_t)dx * NH * NW];
                A[dx][0] = v.x; A[dx][1] = v.y; A[dx][2] = v.z; A[dx][3] = v.w;
            }
        }

#pragma unroll 2
        for (int i = 0; i < 8; ++i) {
            const int c = cg + 8 * i;
            // w[m] = in2[c, r, x0-8+m]; tap (j,dx) needs x0+j+dx-6 -> w[j+dx+2].
            float w[20];
            const float* wp = &lds[c * PITCH + (x0 - X0)];
#pragma unroll
            for (int k = 0; k < 5; ++k) {
                const float4 v = *(const float4*)&wp[4 * k];
                w[4*k+0] = v.x; w[4*k+1] = v.y; w[4*k+2] = v.z; w[4*k+3] = v.w;
            }
#pragma unroll
            for (int dx = 0; dx < WIN; ++dx)
#pragma unroll
                for (int j = 0; j < 4; ++j)
                    acc[i][j] = fmaf(A[dx][j], w[j + dx + 2], acc[i][j]);
        }
    }

    float* ob = out + (((size_t)(b * NC + cg) * NH) + y) * NW + x0;
#pragma unroll
    for (int i = 0; i < 8; ++i) {
        *(float4*)&ob[(size_t)(8 * i) * NH * NW] =
            make_float4(acc[i][0], acc[i][1], acc[i][2], acc[i][3]);
    }
}

extern "C" void kernel_launch(void* const* d_in, const int* in_sizes, int n_in,
                              void* d_out, int out_size, void* d_ws, size_t ws_size,
                              hipStream_t stream) {
    const float* aff = (const float*)d_in[0];   // [4,169,192,192] f32
    const float* in2 = (const float*)d_in[1];   // [4, 64,192,192] f32
    float* outp = (float*)d_out;                // [4, 64,192,192] f32
    dim3 grid(NH, NW / XH, NB);
    dim3 block(NTH);
    hipLaunchKernelGGL(mxassemble, grid, block, 0, stream, aff, in2, outp);
}

// Round 4
// 349.545 us; speedup vs baseline: 3.0441x; 3.0441x over previous
//
#include <hip/hip_runtime.h>

// out[b,c,y,x] = sum_{dy,dx in [0,13)} aff[b, dy*13+dx, y, x] * in2_zp[b, c, y+dy-6, x+dx-6]
// B=4 C=64 H=W=192 D=169.
//
// Round 4 = round 3's conflict-free lane mapping with the spill fixed:
//  - Round 3's `#pragma unroll 2` left acc[i][j] dynamically indexed ->
//    scratch allocation -> 3.4 GB of spill traffic (FETCH 1.8 GB, WRITE
//    1.6 GB, 957 us). Full unroll restores constant indexing.
//  - __launch_bounds__(192,3) resolves to a 6-waves/EU VGPR cap (=84) and
//    guaranteed spill (rounds 1 & 3). amdgpu_waves_per_eu(2) caps at 256
//    and lets the compiler take the ~150 it needs (round-2 idiom).
//  - aff A-loads issued before the staging loop: ~900-cyc global latency
//    overlaps LDS staging + barrier.
//
// Lane mapping (validated by round 3's 3x conflict drop):
//   lane l -> cg = l&7 (channel group), xs = l>>3 (x slot); thread owns
//   channels c = cg + 8i (i=0..7) and 4 x's. LDS row pitch 132
//   (132*4 % 128 == 16B): window b128 bank-quad = (cg + xs + k) % 8 ->
//   exactly 8 lanes/quad = minimum 8 phases, zero conflicts.

#define KD   6
#define WIN  13
#define ND   169
#define NB   4
#define NC   64
#define NH   192
#define NW   192
#define XH   96     // x-half width per block
#define PITCH 132   // LDS row pitch in floats
#define NTH  192    // 3 waves

__global__ __launch_bounds__(NTH)
__attribute__((amdgpu_waves_per_eu(2)))
void mxassemble(const float* __restrict__ aff,
                const float* __restrict__ in2,
                float* __restrict__ out) {
    __shared__ float lds[NC * PITCH];   // 33792 B

    const int y    = blockIdx.x;
    const int half = blockIdx.y;
    const int b    = blockIdx.z;
    const int t    = threadIdx.x;
    const int l    = t & 63;
    const int wv   = t >> 6;            // wave 0..2
    const int cg   = l & 7;             // channel group 0..7
    const int xs   = l >> 3;            // x slot 0..7
    const int X0   = half * XH;
    const int x0   = X0 + wv * 32 + xs * 4;

    // LDS j-index 0 corresponds to global x = X0 - 8; j in [0,112).
    // Pre-zero the 8-float OOB apron per row (left for half 0, right for
    // half 1); staging never touches it again.
    {
        const int jz0 = (half == 0) ? 0 : 104;
        for (int i = t; i < NC * 2; i += NTH) {
            const int c = i >> 1;
            const int q = i & 1;
            *(float4*)&lds[c * PITCH + jz0 + 4 * q] =
                make_float4(0.f, 0.f, 0.f, 0.f);
        }
    }

    float acc[8][4];
#pragma unroll
    for (int i = 0; i < 8; ++i)
#pragma unroll
        for (int j = 0; j < 4; ++j) acc[i][j] = 0.f;

    const float* in2_b = in2 + (size_t)b * NC * NH * NW;
    const float* aff_p = aff + (size_t)b * ND * NH * NW + (size_t)y * NW;

    for (int dy = 0; dy < WIN; ++dy) {
        const int r = y + dy - KD;
        const bool valid = (r >= 0) && (r < NH);   // block-uniform

        __syncthreads();   // previous iteration's readers done

        float A[WIN][4];
        if (valid) {
            // aff[b, dy*13+dx, y, x0..x0+3] -> A[13][4]; issue these global
            // loads FIRST so their latency overlaps the staging below.
            const float* ap = aff_p + (size_t)(dy * WIN) * NH * NW + x0;
#pragma unroll
            for (int dx = 0; dx < WIN; ++dx) {
                const float4 v = *(const float4*)&ap[(size_t)dx * NH * NW];
                A[dx][0] = v.x; A[dx][1] = v.y; A[dx][2] = v.z; A[dx][3] = v.w;
            }

            // Stage in2[b, :, r, X0-8 .. X0+104) -> LDS rows (b128 writes).
            for (int i = t; i < NC * 28; i += NTH) {
                const int c  = i / 28;
                const int q  = i - c * 28;
                const int xg = X0 - 8 + 4 * q;       // global x of this float4
                if (xg >= 0 && xg < NW) {
                    const float4 v =
                        *(const float4*)&in2_b[((size_t)c * NH + r) * NW + xg];
                    *(float4*)&lds[c * PITCH + 4 * q] = v;
                }
            }
        }
        __syncthreads();
        if (!valid) continue;   // zero-padded row contributes nothing

#pragma unroll
        for (int i = 0; i < 8; ++i) {
            const int c = cg + 8 * i;
            // w[m] = in2[c, r, x0-8+m]; tap (j,dx) needs x0+j+dx-6 -> w[j+dx+2].
            float w[20];
            const float* wp = &lds[c * PITCH + (x0 - X0)];
#pragma unroll
            for (int k = 0; k < 5; ++k) {
                const float4 v = *(const float4*)&wp[4 * k];
                w[4*k+0] = v.x; w[4*k+1] = v.y; w[4*k+2] = v.z; w[4*k+3] = v.w;
            }
#pragma unroll
            for (int dx = 0; dx < WIN; ++dx)
#pragma unroll
                for (int j = 0; j < 4; ++j)
                    acc[i][j] = fmaf(A[dx][j], w[j + dx + 2], acc[i][j]);
        }
    }

    float* ob = out + (((size_t)(b * NC + cg) * NH) + y) * NW + x0;
#pragma unroll
    for (int i = 0; i < 8; ++i) {
        *(float4*)&ob[(size_t)(8 * i) * NH * NW] =
            make_float4(acc[i][0], acc[i][1], acc[i][2], acc[i][3]);
    }
}

extern "C" void kernel_launch(void* const* d_in, const int* in_sizes, int n_in,
                              void* d_out, int out_size, void* d_ws, size_t ws_size,
                              hipStream_t stream) {
    const float* aff = (const float*)d_in[0];   // [4,169,192,192] f32
    const float* in2 = (const float*)d_in[1];   // [4, 64,192,192] f32
    float* outp = (float*)d_out;                // [4, 64,192,192] f32
    dim3 grid(NH, NW / XH, NB);
    dim3 block(NTH);
    hipLaunchKernelGGL(mxassemble, grid, block, 0, stream, aff, in2, outp);
}

// Round 6
// 307.822 us; speedup vs baseline: 3.4567x; 1.1355x over previous
//
#include <hip/hip_runtime.h>

// out[b,c,y,x] = sum_{dy,dx in [0,13)} aff[b, dy*13+dx, y, x] * in2_zp[b, c, y+dy-6, x+dx-6]
// B=4 C=64 H=W=192 D=169.
//
// Round 6 = round 5 (fp16 window in LDS + v_dot2_f32_f16, fp32 accumulate)
// with the compile error fixed: __builtin_amdgcn_cvt_pkrtz returns
// __fp16 ext_vector(2), which doesn't convert to _Float16 ext_vector(2);
// route all packing through __builtin_bit_cast(unsigned, ...).
//
//  - Round 4's VGPR_Count=68 < ~104-reg working set => L2-resident scratch
//    spill (23% VALUBusy, 233 us). Shrink the working set: A packs to 28
//    v2f16 regs, window to 10 pairs -> ~90 regs total.
//  - LDS bytes halve (5x ds_read_b64 vs b128 per (i,dy)); 28 dot2 + 8
//    shifts vs 52 fma. LDS = 17.4 KB/block -> higher occupancy cap.
//  - Precision: fp16 quantization of both operands, fp32 accum; abs err
//    ~0.05 << 1.41 threshold.
// Lane mapping (round-3/4, conflict-validated): cg=l&7, xs=l>>3; thread owns
// c = cg+8i and 4 x's. Row pitch 68 words (68%32==4).

#define KD   6
#define WIN  13
#define ND   169
#define NB   4
#define NC   64
#define NH   192
#define NW   192
#define XH   96      // x-half width per block
#define PITCHW 68    // LDS row pitch in 32-bit words (= 136 halves); 68%32==4
#define NTH  192     // 3 waves

typedef _Float16 half2v __attribute__((ext_vector_type(2)));

static __device__ __forceinline__ half2v h2(unsigned u) {
    return __builtin_bit_cast(half2v, u);
}
static __device__ __forceinline__ unsigned pk(float a, float b) {
    return __builtin_bit_cast(unsigned, __builtin_amdgcn_cvt_pkrtz(a, b));
}

#if __has_builtin(__builtin_amdgcn_fdot2)
#define FDOT2(a, b, c) __builtin_amdgcn_fdot2((a), (b), (c), false)
#else
static __device__ __forceinline__ float fdot2_fb(half2v a, half2v b, float c) {
    return fmaf((float)a.x, (float)b.x, fmaf((float)a.y, (float)b.y, c));
}
#define FDOT2(a, b, c) fdot2_fb((a), (b), (c))
#endif

__global__ __launch_bounds__(NTH)
__attribute__((amdgpu_waves_per_eu(2, 4)))
void mxassemble(const float* __restrict__ aff,
                const float* __restrict__ in2,
                float* __restrict__ out) {
    __shared__ unsigned ldsw[NC * PITCHW];   // 17408 B; word = 2 fp16 halves

    const int y    = blockIdx.x;
    const int half = blockIdx.y;
    const int b    = blockIdx.z;
    const int t    = threadIdx.x;
    const int l    = t & 63;
    const int wv   = t >> 6;            // wave 0..2
    const int cg   = l & 7;             // channel group 0..7
    const int xs   = l >> 3;            // x slot 0..7
    const int X0   = half * XH;
    const int x0   = X0 + wv * 32 + xs * 4;

    // Row layout: half-index j in [0,112) maps to global x = X0 - 8 + j.
    // Zero the 8-half OOB apron (j 0..7 for half 0 -> words 0..3;
    // j 104..111 for half 1 -> words 52..55). Staging never touches it.
    {
        const int w0 = (half == 0) ? 0 : 52;
        for (int i = t; i < NC * 2; i += NTH) {
            const int c = i >> 1;
            const int q = i & 1;
            *(uint2*)&ldsw[c * PITCHW + w0 + 2 * q] = make_uint2(0u, 0u);
        }
    }

    float acc[8][4];
#pragma unroll
    for (int i = 0; i < 8; ++i)
#pragma unroll
        for (int j = 0; j < 4; ++j) acc[i][j] = 0.f;

    const float* in2_b = in2 + (size_t)b * NC * NH * NW;
    const float* aff_p = aff + (size_t)b * ND * NH * NW + (size_t)y * NW;

    for (int dy = 0; dy < WIN; ++dy) {
        const int r = y + dy - KD;
        const bool valid = (r >= 0) && (r < NH);   // block-uniform

        __syncthreads();   // previous iteration's readers done

        unsigned Ap[6][4];   // pairs (A[2m], A[2m+1]) per output j
        unsigned Al[4];      // (A[12], 0)
        if (valid) {
            // aff loads first: their latency overlaps the staging below.
            const float* ap = aff_p + (size_t)(dy * WIN) * NH * NW + x0;
            float4 Af[13];
#pragma unroll
            for (int dx = 0; dx < WIN; ++dx)
                Af[dx] = *(const float4*)&ap[(size_t)dx * NH * NW];

            // Stage in2[b, :, r, X0-8 .. X0+104) -> fp16 LDS rows.
            for (int ii = t; ii < NC * 28; ii += NTH) {
                const int c  = ii / 28;
                const int q  = ii - c * 28;
                const int xg = X0 - 8 + 4 * q;
                if (xg >= 0 && xg < NW) {
                    const float4 v =
                        *(const float4*)&in2_b[((size_t)c * NH + r) * NW + xg];
                    uint2 w;
                    w.x = pk(v.x, v.y);
                    w.y = pk(v.z, v.w);
                    *(uint2*)&ldsw[c * PITCHW + 2 * q] = w;
                }
            }

            // Pack A into dx-pairs (fills the pre-barrier waitcnt shadow).
#pragma unroll
            for (int m = 0; m < 6; ++m) {
                Ap[m][0] = pk(Af[2*m].x, Af[2*m+1].x);
                Ap[m][1] = pk(Af[2*m].y, Af[2*m+1].y);
                Ap[m][2] = pk(Af[2*m].z, Af[2*m+1].z);
                Ap[m][3] = pk(Af[2*m].w, Af[2*m+1].w);
            }
            Al[0] = pk(Af[12].x, 0.f);
            Al[1] = pk(Af[12].y, 0.f);
            Al[2] = pk(Af[12].z, 0.f);
            Al[3] = pk(Af[12].w, 0.f);
        }
        __syncthreads();
        if (!valid) continue;

#pragma unroll
        for (int i = 0; i < 8; ++i) {
            const int c = cg + 8 * i;
            // Thread's window: halves h[j0 .. j0+20), j0 = x0-X0 (mult of 4).
            // Tap (j, dx) needs h[j0 + j + dx + 2].
            const unsigned* wp = &ldsw[c * PITCHW + ((x0 - X0) >> 1)];
            const uint2 t0 = *(const uint2*)&wp[0];
            const uint2 t1 = *(const uint2*)&wp[2];
            const uint2 t2 = *(const uint2*)&wp[4];
            const uint2 t3 = *(const uint2*)&wp[6];
            const uint2 t4 = *(const uint2*)&wp[8];
            const unsigned P1 = t0.y, P2 = t1.x, P3 = t1.y, P4 = t2.x;
            const unsigned P5 = t2.y, P6 = t3.x, P7 = t3.y, P8 = t4.x;
            const unsigned P9 = t4.y;
            // Shifted pairs S_m = (h[2m+1], h[2m+2]).
            const unsigned S1 = (P1 >> 16) | (P2 << 16);
            const unsigned S2 = (P2 >> 16) | (P3 << 16);
            const unsigned S3 = (P3 >> 16) | (P4 << 16);
            const unsigned S4 = (P4 >> 16) | (P5 << 16);
            const unsigned S5 = (P5 >> 16) | (P6 << 16);
            const unsigned S6 = (P6 >> 16) | (P7 << 16);
            const unsigned S7 = (P7 >> 16) | (P8 << 16);
            const unsigned S8 = (P8 >> 16) | (P9 << 16);

            float a0 = acc[i][0], a1 = acc[i][1], a2 = acc[i][2], a3 = acc[i][3];
            // j=0: pairs P1..P6, leftover P7.low (Al has 0 in high half)
            a0 = FDOT2(h2(Ap[0][0]), h2(P1), a0);
            a0 = FDOT2(h2(Ap[1][0]), h2(P2), a0);
            a0 = FDOT2(h2(Ap[2][0]), h2(P3), a0);
            a0 = FDOT2(h2(Ap[3][0]), h2(P4), a0);
            a0 = FDOT2(h2(Ap[4][0]), h2(P5), a0);
            a0 = FDOT2(h2(Ap[5][0]), h2(P6), a0);
            a0 = FDOT2(h2(Al[0]),    h2(P7), a0);
            // j=1: S1..S6, leftover S7.low
            a1 = FDOT2(h2(Ap[0][1]), h2(S1), a1);
            a1 = FDOT2(h2(Ap[1][1]), h2(S2), a1);
            a1 = FDOT2(h2(Ap[2][1]), h2(S3), a1);
            a1 = FDOT2(h2(Ap[3][1]), h2(S4), a1);
            a1 = FDOT2(h2(Ap[4][1]), h2(S5), a1);
            a1 = FDOT2(h2(Ap[5][1]), h2(S6), a1);
            a1 = FDOT2(h2(Al[1]),    h2(S7), a1);
            // j=2: P2..P7, leftover P8.low
            a2 = FDOT2(h2(Ap[0][2]), h2(P2), a2);
            a2 = FDOT2(h2(Ap[1][2]), h2(P3), a2);
            a2 = FDOT2(h2(Ap[2][2]), h2(P4), a2);
            a2 = FDOT2(h2(Ap[3][2]), h2(P5), a2);
            a2 = FDOT2(h2(Ap[4][2]), h2(P6), a2);
            a2 = FDOT2(h2(Ap[5][2]), h2(P7), a2);
            a2 = FDOT2(h2(Al[2]),    h2(P8), a2);
            // j=3: S2..S7, leftover S8.low
            a3 = FDOT2(h2(Ap[0][3]), h2(S2), a3);
            a3 = FDOT2(h2(Ap[1][3]), h2(S3), a3);
            a3 = FDOT2(h2(Ap[2][3]), h2(S4), a3);
            a3 = FDOT2(h2(Ap[3][3]), h2(S5), a3);
            a3 = FDOT2(h2(Ap[4][3]), h2(S6), a3);
            a3 = FDOT2(h2(Ap[5][3]), h2(S7), a3);
            a3 = FDOT2(h2(Al[3]),    h2(S8), a3);
            acc[i][0] = a0; acc[i][1] = a1; acc[i][2] = a2; acc[i][3] = a3;
        }
    }

    float* ob = out + (((size_t)(b * NC + cg) * NH) + y) * NW + x0;
#pragma unroll
    for (int i = 0; i < 8; ++i) {
        *(float4*)&ob[(size_t)(8 * i) * NH * NW] =
            make_float4(acc[i][0], acc[i][1], acc[i][2], acc[i][3]);
    }
}

extern "C" void kernel_launch(void* const* d_in, const int* in_sizes, int n_in,
                              void* d_out, int out_size, void* d_ws, size_t ws_size,
                              hipStream_t stream) {
    const float* aff = (const float*)d_in[0];   // [4,169,192,192] f32
    const float* in2 = (const float*)d_in[1];   // [4, 64,192,192] f32
    float* outp = (float*)d_out;                // [4, 64,192,192] f32
    dim3 grid(NH, NW / XH, NB);
    dim3 block(NTH);
    hipLaunchKernelGGL(mxassemble, grid, block, 0, stream, aff, in2, outp);
}